// Round 3
// baseline (1622.196 us; speedup 1.0000x reference)
//
#include <hip/hip_runtime.h>
#include <stdint.h>

// GNN_Layer on MI355X.
// h = relu( xf@W^T + (a_ud@xf)@W_ud^T + (a_lr@xf)@W_lr^T + biases + hg@W_go^T + b_go )
// Restructured: C[8192,512] = a_ud@Y_ud + a_lr@Y_lr + xf@W^T  (K = 16896 concatenated),
// row_add[j] folds all biases + global branch; epilogue relu.
//
// R5 -> R6: k5 rebuilt as a barrier-free, LDS-free direct GEMM.
//  R5 lesson: +8 VGPR crossed the 128 unified-reg cliff (72 VGPR + 64 AGPR = 136)
//  -> occupancy 39.7% -> 25.3% (4 -> 2 blocks/CU), dur 430 -> 520us, even though
//  FETCH improved 790 -> 592 MB. Latency-bound kernel lives and dies on TLP.
//  Structural insight: A has ZERO intra-block reuse (each element feeds exactly one
//  lane's fragment) and B is LLC-resident (17 MB) -- LDS staging + barriers were
//  pure overhead coupling cold-HBM A latency into block-wide barrier stalls.
//  New k5: wave tile 64x32 (acc 32 AGPR), A and B fragments loaded global->VGPR
//  with 2 rotating sets each (2-body cover ~600cy), fp32->bf16 convert in-register.
//  No LDS, no barriers, no asm: per-wave in-order vmcnt queue gives counted-wait
//  semantics (oldest set drained, younger stays in flight). 80 staging VGPR + 32
//  AGPR fits <=128 unified -> 16 waves/CU enforced by __launch_bounds__(256,4).
//
// Workspace:
//   xb      bf16[8192][512]   @ 0
//   Yt      bf16[512][16896]  @ 8,388,608    k<8192: Y_ud^T | <16384: Y_lr^T | tail: W
//   Wb1     bf16[1536][512]   @ 25,690,112   rows: W_ud | W_lr | W_g
//   colsum  f32[512]          @ 27,262,976
//   row_add f32[512]          @ 27,265,024
//   P       f32[Z-1][8192][512] @ 27,267,072 split-K partials

typedef __attribute__((ext_vector_type(8))) short short8;   // 8 bf16 = 4 VGPRs
typedef __attribute__((ext_vector_type(4))) float f32x4;    // MFMA C/D frag

typedef const __attribute__((address_space(1))) void* gas1_t;
typedef __attribute__((address_space(3))) void* las3_t;

__device__ __forceinline__ void gload16(const void* g, void* l) {
  __builtin_amdgcn_global_load_lds((gas1_t)g, (las3_t)l, 16, 0, 0);
}

// pack two fp32 -> two bf16 by truncation (top halves), one v_perm_b32
__device__ __forceinline__ unsigned pack2t(float lo, float hi) {
  return __builtin_amdgcn_perm(__float_as_uint(hi), __float_as_uint(lo), 0x07060302u);
}

// round-to-nearest-even fp32 -> bf16
__device__ __forceinline__ unsigned f2bf_rne(float f) {
  unsigned u = __float_as_uint(f);
  return (u + 0x7FFFu + ((u >> 16) & 1u)) >> 16;
}
__device__ __forceinline__ unsigned pack2_rne(float lo, float hi) {
  return f2bf_rne(lo) | (f2bf_rne(hi) << 16);
}

// ---------------- K1: dtype conversion ----------------
__global__ __launch_bounds__(256) void k1_convert(
    const float* __restrict__ x, const float* __restrict__ W,
    const float* __restrict__ W_ud, const float* __restrict__ W_lr,
    const float* __restrict__ W_g,
    uint16_t* __restrict__ xb, uint16_t* __restrict__ Yt, uint16_t* __restrict__ Wb1)
{
  unsigned tid = blockIdx.x * 256u + threadIdx.x;   // 0..655359
  const float* src;
  uint16_t* dst;
  if (tid < 524288u) {
    src = x + (size_t)tid * 8;
    dst = xb + (size_t)tid * 8;
  } else {
    unsigned r = tid - 524288u;
    unsigned which = r >> 15;              // 0:W 1:W_ud 2:W_lr 3:W_g
    unsigned e8 = (r & 32767u) * 8;
    src = (which == 0 ? W : which == 1 ? W_ud : which == 2 ? W_lr : W_g) + e8;
    if (which == 0) {
      unsigned n = e8 >> 9, k = e8 & 511u;
      dst = Yt + (size_t)n * 16896 + 16384 + k;
    } else {
      dst = Wb1 + (size_t)(which - 1) * 262144 + e8;
    }
  }
  float4 v0 = ((const float4*)src)[0];
  float4 v1 = ((const float4*)src)[1];
  uint4 p;
  p.x = pack2_rne(v0.x, v0.y); p.y = pack2_rne(v0.z, v0.w);
  p.z = pack2_rne(v1.x, v1.y); p.w = pack2_rne(v1.z, v1.w);
  *(uint4*)dst = p;
}

// ---------------- K2: small GEMM  Z = xb @ Wb1^T  (M=8192, N=1536, K=512) ----------------
// blockIdx.y 0-3 -> Y_ud^T; 4-7 -> Y_lr^T; 8-11 -> colsum += mask*relu(Z+b_g)
// Double-buffered gload_lds staging + chunk-XOR swizzle (64B LDS rows, conflict-free).
__global__ __launch_bounds__(256) void k2_gemm1(
    const uint16_t* __restrict__ xb, const uint16_t* __restrict__ Wb1,
    const float* __restrict__ mask, const float* __restrict__ b_g,
    uint16_t* __restrict__ Yt, float* __restrict__ colsum)
{
  __shared__ __align__(16) char smem[34816];
  char* const A0 = smem;
  char* const B0 = smem + 8192;
  char* const A1 = smem + 16384;
  char* const B1 = smem + 24576;

  const int t = threadIdx.x;
  const int i0 = blockIdx.x * 128;
  const int bn = blockIdx.y;
  const int n0 = bn * 128;
  const int lane = t & 63, w = t >> 6;
  const int q = lane >> 4, l15 = lane & 15;
  const int wm = w >> 1, wn = w & 1;
  const int srow = t >> 2;
  const int sw = (t & 3) ^ ((srow >> 1) & 3);   // swizzled source chunk

  f32x4 acc[4][4] = {};

  const uint16_t* const aA0 = xb + (size_t)(i0 + srow) * 512 + sw * 8;
  const uint16_t* const aA1 = aA0 + (size_t)64 * 512;
  const uint16_t* const aB0 = Wb1 + (size_t)(n0 + srow) * 512 + sw * 8;
  const uint16_t* const aB1 = aB0 + (size_t)64 * 512;

  // prologue: stage step 0
  gload16(aA0, A0 + t * 16);
  gload16(aA1, A0 + 4096 + t * 16);
  gload16(aB0, B0 + t * 16);
  gload16(aB1, B0 + 4096 + t * 16);

  for (int s = 0; s < 16; ++s) {
    __syncthreads();                       // drains step-s loads (issued last iter)
    if (s < 15) {
      const int kk = (s + 1) << 5;
      char* const nA = (s & 1) ? A0 : A1;
      char* const nB = (s & 1) ? B0 : B1;
      gload16(aA0 + kk, nA + t * 16);
      gload16(aA1 + kk, nA + 4096 + t * 16);
      gload16(aB0 + kk, nB + t * 16);
      gload16(aB1 + kk, nB + 4096 + t * 16);
    }
    char* const cA = (s & 1) ? A1 : A0;
    char* const cB = (s & 1) ? B1 : B0;
    short8 af[4], bf[4];
#pragma unroll
    for (int mi = 0; mi < 4; ++mi) {
      const int r = wm * 64 + mi * 16 + l15;
      af[mi] = *(const short8*)(cA + r * 64 + ((q ^ ((r >> 1) & 3)) * 16));
    }
#pragma unroll
    for (int ni = 0; ni < 4; ++ni) {
      const int r = wn * 64 + ni * 16 + l15;
      bf[ni] = *(const short8*)(cB + r * 64 + ((q ^ ((r >> 1) & 3)) * 16));
    }
#pragma unroll
    for (int mi = 0; mi < 4; ++mi)
#pragma unroll
      for (int ni = 0; ni < 4; ++ni)
        acc[mi][ni] = __builtin_amdgcn_mfma_f32_16x16x32_bf16(af[mi], bf[ni], acc[mi][ni], 0, 0, 0);
  }
  __syncthreads();

  const int g = bn >> 2;            // 0: ud, 1: lr, 2: g-branch
  const int jb = (bn & 3) * 128;

  if (g < 2) {
    // transpose 128x128 tile through LDS, emit bf16 rows of Yt
    uint16_t* T = (uint16_t*)smem;  // [128][136]
#pragma unroll
    for (int mi = 0; mi < 4; ++mi) {
#pragma unroll
      for (int ni = 0; ni < 4; ++ni) {
        int jl = wn * 64 + ni * 16 + l15;
#pragma unroll
        for (int r = 0; r < 4; ++r) {
          int il = wm * 64 + mi * 16 + q * 4 + r;
          T[jl * 136 + il] = (uint16_t)f2bf_rne(acc[mi][ni][r]);
        }
      }
    }
    __syncthreads();
    const int jl = t >> 1, half = t & 1;
    uint16_t* dst = Yt + (size_t)(jb + jl) * 16896 + (size_t)g * 8192 + i0 + half * 64;
    const uint16_t* srcT = T + jl * 136 + half * 64;
#pragma unroll
    for (int c = 0; c < 8; ++c)
      *(uint4*)(dst + c * 8) = *(const uint4*)(srcT + c * 8);
  } else {
    // fused global-branch reduction: colsum[j] += sum_i mask[i]*relu(Z[i][j]+b_g[j])
    float mk[4][4];
#pragma unroll
    for (int mi = 0; mi < 4; ++mi)
#pragma unroll
      for (int r = 0; r < 4; ++r)
        mk[mi][r] = mask[i0 + wm * 64 + mi * 16 + q * 4 + r];
#pragma unroll
    for (int ni = 0; ni < 4; ++ni) {
      const int jl = jb + wn * 64 + ni * 16 + l15;
      const float bg = b_g[jl];
      float p = 0.f;
#pragma unroll
      for (int mi = 0; mi < 4; ++mi)
#pragma unroll
        for (int r = 0; r < 4; ++r)
          p += fmaxf(acc[mi][ni][r] + bg, 0.f) * mk[mi][r];
      p += __shfl_xor(p, 16);
      p += __shfl_xor(p, 32);
      if (q == 0) atomicAdd(&colsum[jl], p);
    }
  }
}

// ---------------- K4: h_g, row_add ----------------
__global__ __launch_bounds__(256) void k4_finalize(
    const float* __restrict__ colsum, const float* __restrict__ mask,
    const float* __restrict__ b, const float* __restrict__ b_ud,
    const float* __restrict__ b_lr, const float* __restrict__ W_go,
    const float* __restrict__ b_go,
    float* __restrict__ row_add, float* __restrict__ out_hg)
{
  __shared__ float red[256];
  __shared__ float hg[512];
  const int t = threadIdx.x;
  float s = 0.f;
  for (int k = t; k < 8192; k += 256) s += mask[k];
  red[t] = s;
  __syncthreads();
  for (int o = 128; o > 0; o >>= 1) {
    if (t < o) red[t] += red[t + o];
    __syncthreads();
  }
  const float n = red[0];
  for (int j = t; j < 512; j += 256) hg[j] = colsum[j] / n;
  __syncthreads();

  const int j0 = blockIdx.x * 64;
  const int jj = j0 + (t >> 2);
  const int seg = t & 3;
  const float4* wrow = (const float4*)(W_go + (size_t)jj * 512 + seg * 128);
  float p = 0.f;
#pragma unroll 4
  for (int c = 0; c < 32; ++c) {
    float4 wv = wrow[c];
    const float* h4 = &hg[seg * 128 + c * 4];
    p += wv.x * h4[0] + wv.y * h4[1] + wv.z * h4[2] + wv.w * h4[3];
  }
  p += __shfl_down(p, 2);
  p += __shfl_down(p, 1);
  if ((t & 3) == 0)
    row_add[jj] = b[jj] + b_ud[jj] + b_lr[jj] + b_go[jj] + p;
  if (t < 64) out_hg[j0 + t] = hg[j0 + t];
}

// ---------------- K5: big GEMM, K=16896, split-K xZ — direct, barrier-free ----------------
// BM=128 BN=64 BK=32; grid (64, 8, Z); 4 waves (2x2), wave tile 64x32, acc 32 AGPR.
// A fragments: global fp32 -> 2 rotating float4[4][2] sets (2-body cover), converted
// to bf16 at use (4 v_perm per fragment). B fragments: Yt bf16 -> 2 rotating short8[2]
// sets. No LDS, no barriers: per-wave in-order vmcnt queue = implicit counted waits.
// z=0 -> out, z>0 -> P[(z-1)]; K6 combines.
__global__ __launch_bounds__(256, 4) void k5_gemm_big(
    const float* __restrict__ a_ud, const float* __restrict__ a_lr,
    const float* __restrict__ x, const uint16_t* __restrict__ Yt,
    float* __restrict__ out, float* __restrict__ P, int nsteps)
{
  const int t = threadIdx.x;
  const int i0 = blockIdx.x * 128;
  const int j0 = blockIdx.y * 64;
  const int z  = blockIdx.z;
  const int lane = t & 63;
  const int q = lane >> 4, l15 = lane & 15;
  const int w = t >> 6;
  const int wm = w >> 1, wn = w & 1;        // 2x2 waves; wave tile 64(m) x 32(n)

  f32x4 acc[4][2] = {};
  const int kbase0 = z * (nsteps << 5);
  const int arow0 = i0 + wm * 64 + l15;     // A row base for this lane (+ mi*16)

  float4 aX[4][2], aY[4][2];                // two rotating A sets (32 VGPR each)
  short8 bX[2], bY[2];                      // two rotating B sets (8 VGPR each)

  // A source select: BK=32 never straddles a segment boundary (all mult. of 32).
#define LOAD_A_SET(dst, gk_) { \
    const int gk5_ = (gk_); \
    const float* base5_; int ld5_; int kk5_; \
    if (gk5_ < 8192)       { base5_ = a_ud; ld5_ = 8192; kk5_ = gk5_; } \
    else if (gk5_ < 16384) { base5_ = a_lr; ld5_ = 8192; kk5_ = gk5_ - 8192; } \
    else                   { base5_ = x;    ld5_ = 512;  kk5_ = gk5_ - 16384; } \
    const float* ap5_ = base5_ + (size_t)arow0 * ld5_ + kk5_ + q * 8; \
    _Pragma("unroll") \
    for (int mi_ = 0; mi_ < 4; ++mi_) { \
      const float* r5_ = ap5_ + (size_t)(mi_ * 16) * ld5_; \
      dst[mi_][0] = ((const float4*)r5_)[0]; \
      dst[mi_][1] = ((const float4*)r5_)[1]; \
    } }

#define LOAD_B_SET(dst, gk_) { \
    _Pragma("unroll") \
    for (int ni_ = 0; ni_ < 2; ++ni_) { \
      const uint16_t* bp5_ = Yt + (size_t)(j0 + wn * 32 + ni_ * 16 + l15) * 16896 \
                              + (gk_) + q * 8; \
      dst[ni_] = *(const short8*)bp5_; \
    } }

  // convert A set to bf16 per-fragment and run the 8 MFMAs of one K-step
#define K5_BODY(av, bv) { \
    _Pragma("unroll") \
    for (int mi_ = 0; mi_ < 4; ++mi_) { \
      uint4 u5_; \
      u5_.x = pack2t(av[mi_][0].x, av[mi_][0].y); \
      u5_.y = pack2t(av[mi_][0].z, av[mi_][0].w); \
      u5_.z = pack2t(av[mi_][1].x, av[mi_][1].y); \
      u5_.w = pack2t(av[mi_][1].z, av[mi_][1].w); \
      short8 af5_ = *(short8*)&u5_; \
      acc[mi_][0] = __builtin_amdgcn_mfma_f32_16x16x32_bf16(af5_, bv[0], acc[mi_][0], 0, 0, 0); \
      acc[mi_][1] = __builtin_amdgcn_mfma_f32_16x16x32_bf16(af5_, bv[1], acc[mi_][1], 0, 0, 0); \
    } }

  // prologue: fill both pipeline stages (queue: aX8,bX2,aY8,bY2 — oldest first)
  LOAD_A_SET(aX, kbase0);
  LOAD_B_SET(bX, kbase0);
  LOAD_A_SET(aY, kbase0 + 32);
  LOAD_B_SET(bY, kbase0 + 32);

  // steady state: consuming set s waits only its own (oldest) loads; the loads
  // issued right after each body get ~2 bodies of flight time before use.
  for (int s = 0; s < nsteps - 2; s += 2) {
    K5_BODY(aX, bX);
    LOAD_A_SET(aX, kbase0 + ((s + 2) << 5));
    LOAD_B_SET(bX, kbase0 + ((s + 2) << 5));
    K5_BODY(aY, bY);
    LOAD_A_SET(aY, kbase0 + ((s + 3) << 5));
    LOAD_B_SET(bY, kbase0 + ((s + 3) << 5));
  }
  K5_BODY(aX, bX);
  K5_BODY(aY, bY);

#undef K5_BODY
#undef LOAD_B_SET
#undef LOAD_A_SET

  float* dst = z ? P + (size_t)(z - 1) * 4194304 : out;
#pragma unroll
  for (int ni = 0; ni < 2; ++ni) {
    const int jl = j0 + wn * 32 + ni * 16 + l15;
#pragma unroll
    for (int mi = 0; mi < 4; ++mi)
#pragma unroll
      for (int r = 0; r < 4; ++r) {
        const int il = i0 + wm * 64 + mi * 16 + q * 4 + r;
        dst[(size_t)il * 512 + jl] = acc[mi][ni][r];
      }
  }
}

// ---------------- K6: combine split-K partials + row_add + relu ----------------
__global__ __launch_bounds__(256) void k6_combine(
    const float* __restrict__ P, const float* __restrict__ row_add,
    float* __restrict__ out, int npart)
{
  const int idx = blockIdx.x * 256 + threadIdx.x;     // float4 index, 1048576 total
  float4 a = ((const float4*)out)[idx];
  for (int p = 0; p < npart; ++p) {
    const float4 v = ((const float4*)P)[(size_t)p * 1048576 + idx];
    a.x += v.x; a.y += v.y; a.z += v.z; a.w += v.w;
  }
  const float4 r = ((const float4*)row_add)[idx & 127];
  float4 o;
  o.x = fmaxf(a.x + r.x, 0.f);
  o.y = fmaxf(a.y + r.y, 0.f);
  o.z = fmaxf(a.z + r.z, 0.f);
  o.w = fmaxf(a.w + r.w, 0.f);
  ((float4*)out)[idx] = o;
}

extern "C" void kernel_launch(void* const* d_in, const int* in_sizes, int n_in,
                              void* d_out, int out_size, void* d_ws, size_t ws_size,
                              hipStream_t stream) {
  (void)in_sizes; (void)n_in; (void)out_size;
  const float* x    = (const float*)d_in[0];
  const float* mask = (const float*)d_in[1];
  const float* a_ud = (const float*)d_in[2];
  const float* a_lr = (const float*)d_in[3];
  const float* W    = (const float*)d_in[4];
  const float* b    = (const float*)d_in[5];
  const float* W_ud = (const float*)d_in[6];
  const float* b_ud = (const float*)d_in[7];
  const float* W_lr = (const float*)d_in[8];
  const float* b_lr = (const float*)d_in[9];
  const float* W_g  = (const float*)d_in[10];
  const float* b_g  = (const float*)d_in[11];
  const float* W_go = (const float*)d_in[12];
  const float* b_go = (const float*)d_in[13];
  float* out = (float*)d_out;

  char* ws = (char*)d_ws;
  uint16_t* xb     = (uint16_t*)(ws);
  uint16_t* Yt     = (uint16_t*)(ws + 8388608);
  uint16_t* Wb1    = (uint16_t*)(ws + 25690112);
  float*    colsum = (float*)(ws + 27262976);
  float*    rowadd = (float*)(ws + 27265024);
  float*    P      = (float*)(ws + 27267072);

  // ws gate: z=4 needs 3 partials (77.6 MB); fall back to z=2 (1 partial, 44 MB proven).
  const int Z = (ws_size >= 77598720u) ? 4 : 2;
  const int nsteps = (16896 / Z) / 32;   // 132 (Z=4) or 264 (Z=2): even, >=4

  hipMemsetAsync(colsum, 0, 512 * sizeof(float), stream);
  k1_convert<<<2560, 256, 0, stream>>>(x, W, W_ud, W_lr, W_g, xb, Yt, Wb1);
  k2_gemm1<<<dim3(64, 12), 256, 0, stream>>>(xb, Wb1, mask, b_g, Yt, colsum);
  k4_finalize<<<8, 256, 0, stream>>>(colsum, mask, b, b_ud, b_lr, W_go, b_go,
                                     rowadd, out + 4194304);
  k5_gemm_big<<<dim3(64, 8, Z), 256, 0, stream>>>(a_ud, a_lr, x, Yt, out, P, nsteps);
  k6_combine<<<4096, 256, 0, stream>>>(P, rowadd, out, Z - 1);
}